// Round 1
// baseline (1776.794 us; speedup 1.0000x reference)
//
#include <hip/hip_runtime.h>
#include <hip/hip_bf16.h>

// Problem constants (from reference)
constexpr int WIDTH   = 16;
constexpr int HID     = 512;
constexpr int NHEADS  = 8;
constexpr int DK      = 64;      // HID / NHEADS
constexpr int NLAYERS = 2;
constexpr int NHW     = 2;
constexpr int B       = 4;
constexpr int S       = 1024;
constexpr int PAD     = S + 2 * WIDTH;   // 1056

// ---------------------------------------------------------------------------
// build padded sequence: xp[b, p, c] = front[p][c] (p<W) | x[b, p-W, c] | back[p-W-S][c]
// float4 over B*PAD*HID/4 elements
// ---------------------------------------------------------------------------
__global__ __launch_bounds__(256) void build_pad(
    const float* __restrict__ x,      // [B, S, HID]
    const float* __restrict__ front,  // [WIDTH, HID]
    const float* __restrict__ back,   // [WIDTH, HID]
    float* __restrict__ xp)           // [B, PAD, HID]
{
    int idx = blockIdx.x * 256 + threadIdx.x;          // over B*PAD*(HID/4)
    int c4  = idx & 127;                               // HID/4 = 128
    int rest = idx >> 7;
    int p = rest % PAD;
    int b = rest / PAD;
    float4 val;
    if (p < WIDTH) {
        val = *(const float4*)(front + (size_t)p * HID + c4 * 4);
    } else if (p < WIDTH + S) {
        val = *(const float4*)(x + ((size_t)b * S + (p - WIDTH)) * HID + c4 * 4);
    } else {
        val = *(const float4*)(back + (size_t)(p - WIDTH - S) * HID + c4 * 4);
    }
    *(float4*)(xp + ((size_t)b * PAD + p) * HID + c4 * 4) = val;
}

// ---------------------------------------------------------------------------
// C[M,N] = A[M,K] @ B[N,K]^T + bias[N]   (torch Linear layout, NT GEMM)
// 64x64 tile, BK=16, 256 threads, 4x4 acc/thread, float4 global loads.
// Requires M%64==0, N%64==0, K%16==0 (true for all call sites here).
// ---------------------------------------------------------------------------
constexpr int BM = 64, BN = 64, BKT = 16;

__global__ __launch_bounds__(256) void gemm_nt_bias(
    const float* __restrict__ A, const float* __restrict__ Bw,
    const float* __restrict__ bias, float* __restrict__ C,
    int M, int N, int K)
{
    __shared__ float As[BKT][BM + 4];
    __shared__ float Bs[BKT][BN + 4];

    int tid = threadIdx.x;
    int bm = blockIdx.y * BM;
    int bn = blockIdx.x * BN;
    int tx = tid & 15;        // 0..15 -> n groups of 4
    int ty = tid >> 4;        // 0..15 -> m groups of 4
    int lm = tid >> 2;        // 0..63 : row within tile for staging load
    int lk = (tid & 3) * 4;   // 0,4,8,12 : k offset for staging load

    const float* Ap = A  + (size_t)(bm + lm) * K + lk;
    const float* Bp = Bw + (size_t)(bn + lm) * K + lk;

    float acc[4][4] = {};

    for (int k0 = 0; k0 < K; k0 += BKT) {
        float4 a4 = *(const float4*)(Ap + k0);
        float4 b4 = *(const float4*)(Bp + k0);
        As[lk + 0][lm] = a4.x; As[lk + 1][lm] = a4.y;
        As[lk + 2][lm] = a4.z; As[lk + 3][lm] = a4.w;
        Bs[lk + 0][lm] = b4.x; Bs[lk + 1][lm] = b4.y;
        Bs[lk + 2][lm] = b4.z; Bs[lk + 3][lm] = b4.w;
        __syncthreads();
        #pragma unroll
        for (int kk = 0; kk < BKT; ++kk) {
            float ar[4], br[4];
            #pragma unroll
            for (int i = 0; i < 4; ++i) ar[i] = As[kk][ty * 4 + i];
            #pragma unroll
            for (int j = 0; j < 4; ++j) br[j] = Bs[kk][tx * 4 + j];
            #pragma unroll
            for (int i = 0; i < 4; ++i)
                #pragma unroll
                for (int j = 0; j < 4; ++j)
                    acc[i][j] += ar[i] * br[j];
        }
        __syncthreads();
    }

    float4 bb = *(const float4*)(bias + bn + tx * 4);
    #pragma unroll
    for (int i = 0; i < 4; ++i) {
        int row = bm + ty * 4 + i;
        float4 o4;
        o4.x = acc[i][0] + bb.x;
        o4.y = acc[i][1] + bb.y;
        o4.z = acc[i][2] + bb.z;
        o4.w = acc[i][3] + bb.w;
        *(float4*)(C + (size_t)row * N + bn + tx * 4) = o4;
    }
}

// ---------------------------------------------------------------------------
// Banded multi-head attention. One wave per (b, h, query i); lane = dk index.
// forward:  keys j in [i-WIDTH-1, i]   (clipped to [0, PAD-1])
// backward: keys j in [i, i+WIDTH+1]
// ---------------------------------------------------------------------------
__global__ __launch_bounds__(256) void banded_attn(
    const float* __restrict__ Q, const float* __restrict__ Kt,
    const float* __restrict__ V, float* __restrict__ O, int backward)
{
    int w    = blockIdx.x * 4 + (threadIdx.x >> 6);   // wave index over B*NH*PAD
    int lane = threadIdx.x & 63;
    int i  = w % PAD;
    int bh = w / PAD;
    int h  = bh & (NHEADS - 1);
    int b  = bh / NHEADS;

    int jlo, jhi;
    if (backward) {
        jlo = i;
        jhi = i + WIDTH + 1; if (jhi > PAD - 1) jhi = PAD - 1;
    } else {
        jlo = i - WIDTH - 1; if (jlo < 0) jlo = 0;
        jhi = i;
    }
    int n = jhi - jlo + 1;

    size_t base = (size_t)b * PAD * HID + h * DK + lane;
    float qd = Q[base + (size_t)i * HID];

    float sc[WIDTH + 2];
    for (int t = 0; t < n; ++t) {
        float p = qd * Kt[base + (size_t)(jlo + t) * HID];
        #pragma unroll
        for (int off = 32; off > 0; off >>= 1) p += __shfl_xor(p, off);
        sc[t] = p * 0.125f;   // 1/sqrt(64)
    }
    float m = -1e30f;
    for (int t = 0; t < n; ++t) m = fmaxf(m, sc[t]);
    float denom = 0.f;
    for (int t = 0; t < n; ++t) { sc[t] = __expf(sc[t] - m); denom += sc[t]; }
    float inv = 1.0f / denom;
    float od = 0.f;
    for (int t = 0; t < n; ++t) od += sc[t] * V[base + (size_t)(jlo + t) * HID];
    O[base + (size_t)i * HID] = od * inv;
}

// ---------------------------------------------------------------------------
// rel combine: out[b,t,c] = att[b, WIDTH+t, c] + sum_{k=0..16} w[k]*att[b, offset+k+t, c]
// float4 over B*S*HID/4
// ---------------------------------------------------------------------------
__global__ __launch_bounds__(256) void rel_combine(
    const float* __restrict__ att,    // [B, PAD, HID]
    const float* __restrict__ w,      // [WIDTH+1]
    float* __restrict__ out,          // [B, S, HID]
    int offset)
{
    int idx = blockIdx.x * 256 + threadIdx.x;   // over B*S*128
    int c4 = idx & 127;
    int rest = idx >> 7;
    int t = rest & (S - 1);
    int b = rest >> 10;

    const float* rowbase = att + (size_t)b * PAD * HID + c4 * 4;
    float4 acc = *(const float4*)(rowbase + (size_t)(WIDTH + t) * HID);
    #pragma unroll
    for (int k = 0; k <= WIDTH; ++k) {
        float wk = w[k];
        float4 xv = *(const float4*)(rowbase + (size_t)(offset + k + t) * HID);
        acc.x += wk * xv.x; acc.y += wk * xv.y;
        acc.z += wk * xv.z; acc.w += wk * xv.w;
    }
    *(float4*)(out + ((size_t)b * S + t) * HID + c4 * 4) = acc;
}

// ---------------------------------------------------------------------------
// highway gate: out = sigmoid(g)*x + (1-sigmoid(g))*relu(nl)
// proj is [B*S, 2*HID]: nl at col c, gate at col HID+c. float4 over B*S*HID/4.
// ---------------------------------------------------------------------------
__global__ __launch_bounds__(256) void highway_gate(
    const float* __restrict__ x, const float* __restrict__ proj,
    float* __restrict__ out)
{
    int idx = blockIdx.x * 256 + threadIdx.x;   // over B*S*128
    int c4 = idx & 127;
    int r  = idx >> 7;
    float4 nl = *(const float4*)(proj + (size_t)r * (2 * HID) + c4 * 4);
    float4 g  = *(const float4*)(proj + (size_t)r * (2 * HID) + HID + c4 * 4);
    float4 xv = *(const float4*)(x + (size_t)idx * 4);
    float4 o;
    float sg;
    sg  = 1.f / (1.f + __expf(-g.x)); o.x = sg * xv.x + (1.f - sg) * fmaxf(nl.x, 0.f);
    sg  = 1.f / (1.f + __expf(-g.y)); o.y = sg * xv.y + (1.f - sg) * fmaxf(nl.y, 0.f);
    sg  = 1.f / (1.f + __expf(-g.z)); o.z = sg * xv.z + (1.f - sg) * fmaxf(nl.z, 0.f);
    sg  = 1.f / (1.f + __expf(-g.w)); o.w = sg * xv.w + (1.f - sg) * fmaxf(nl.w, 0.f);
    *(float4*)(out + (size_t)idx * 4) = o;
}

// ---------------------------------------------------------------------------
// out[l, b, t, 0:HID] = f, out[l, b, t, HID:2HID] = bk.  float4 over B*S*2H/4
// ---------------------------------------------------------------------------
__global__ __launch_bounds__(256) void write_out(
    const float* __restrict__ f, const float* __restrict__ bk,
    float* __restrict__ out)   // out already offset to layer base
{
    int idx = blockIdx.x * 256 + threadIdx.x;   // over B*S*256
    int c4 = idx & 255;                         // 2*HID/4 = 256
    int r  = idx >> 8;                          // b*S + t
    float4 v;
    if (c4 < 128) v = *(const float4*)(f  + (size_t)r * HID + c4 * 4);
    else          v = *(const float4*)(bk + (size_t)r * HID + (c4 - 128) * 4);
    *(float4*)(out + (size_t)r * (2 * HID) + c4 * 4) = v;
}

// ---------------------------------------------------------------------------
extern "C" void kernel_launch(void* const* d_in, const int* in_sizes, int n_in,
                              void* d_out, int out_size, void* d_ws, size_t ws_size,
                              hipStream_t stream)
{
    const float* inputs   = (const float*)d_in[0];
    // d_in[1] = masks (unused by reference body)
    const float* fw_lin_w = (const float*)d_in[2];
    const float* fw_lin_b = (const float*)d_in[3];
    const float* bw_lin_w = (const float*)d_in[4];
    const float* bw_lin_b = (const float*)d_in[5];
    const float* fw_hw_w  = (const float*)d_in[6];
    const float* fw_hw_b  = (const float*)d_in[7];
    const float* bw_hw_w  = (const float*)d_in[8];
    const float* bw_hw_b  = (const float*)d_in[9];
    const float* fw_pad   = (const float*)d_in[10];
    const float* bw_pad   = (const float*)d_in[11];
    const float* fw_rel   = (const float*)d_in[12];
    const float* bw_rel   = (const float*)d_in[13];
    float* out = (float*)d_out;
    float* ws  = (float*)d_ws;

    const size_t BSH = (size_t)B * S * HID;     // 2,097,152
    const size_t BPH = (size_t)B * PAD * HID;   // 2,162,688

    float* f    = ws;            // persists across layer
    float* bk   = f  + BSH;      // persists across layer
    float* xpad = bk + BSH;
    float* q    = xpad + BPH;
    float* k    = q  + BPH;
    float* v    = k  + BPH;
    float* o    = v  + BPH;
    // aliases (lifetimes do not overlap):
    float* att  = q;             // out-proj result (q dead after attn)
    float* fo   = o;             // rel output     (o dead after out-proj)
    float* hw   = k;             // highway proj, needs B*S*2H = 4.19M <= k..v span 4.33M

    const int MP = B * PAD;   // 4224
    const int MS = B * S;     // 4096

    dim3 gP(HID / BN, MP / BM);        // (8, 66)
    dim3 gH(2 * HID / BN, MS / BM);    // (16, 64)

    for (int l = 0; l < NLAYERS; ++l) {
        for (int dir = 0; dir < 2; ++dir) {
            const float* src   = (l == 0) ? inputs : (dir ? bk : f);
            const float* lin_w = (dir ? bw_lin_w : fw_lin_w) + (size_t)l * 4 * HID * HID;
            const float* lin_b = (dir ? bw_lin_b : fw_lin_b) + (size_t)l * 4 * HID;
            const float* hw_w  = (dir ? bw_hw_w  : fw_hw_w ) + (size_t)l * NHW * 2 * HID * HID;
            const float* hw_b  = (dir ? bw_hw_b  : fw_hw_b ) + (size_t)l * NHW * 2 * HID;
            const float* relw  = (dir ? bw_rel   : fw_rel  ) + (size_t)l * (WIDTH + 1);
            const float* front = fw_pad + (size_t)l * WIDTH * HID;   // fw_pad front for BOTH dirs
            const float* back  = bw_pad + (size_t)l * WIDTH * HID;   // bw_pad back  for BOTH dirs
            float* dst = dir ? bk : f;

            build_pad<<<(B * PAD * HID / 4) / 256, 256, 0, stream>>>(src, front, back, xpad);

            gemm_nt_bias<<<gP, 256, 0, stream>>>(xpad, lin_w + 0 * HID * HID,
                                                 lin_b + 0 * HID, q, MP, HID, HID);
            gemm_nt_bias<<<gP, 256, 0, stream>>>(xpad, lin_w + 1 * HID * HID,
                                                 lin_b + 1 * HID, k, MP, HID, HID);
            gemm_nt_bias<<<gP, 256, 0, stream>>>(xpad, lin_w + 2 * HID * HID,
                                                 lin_b + 2 * HID, v, MP, HID, HID);

            banded_attn<<<(B * NHEADS * PAD) / 4, 256, 0, stream>>>(q, k, v, o, dir);

            gemm_nt_bias<<<gP, 256, 0, stream>>>(o, lin_w + 3 * (size_t)HID * HID,
                                                 lin_b + 3 * HID, att, MP, HID, HID);

            rel_combine<<<(B * S * HID / 4) / 256, 256, 0, stream>>>(
                att, relw, fo, dir ? WIDTH : 0);

            for (int i = 0; i < NHW; ++i) {
                gemm_nt_bias<<<gH, 256, 0, stream>>>(fo, hw_w + (size_t)i * 2 * HID * HID,
                                                     hw_b + (size_t)i * 2 * HID, hw,
                                                     MS, 2 * HID, HID);
                highway_gate<<<(B * S * HID / 4) / 256, 256, 0, stream>>>(
                    fo, hw, (i == NHW - 1) ? dst : fo);
            }
        }
        write_out<<<(B * S * 2 * HID / 4) / 256, 256, 0, stream>>>(
            f, bk, out + (size_t)l * B * S * 2 * HID);
    }
}

// Round 3
// 1149.834 us; speedup vs baseline: 1.5453x; 1.5453x over previous
//
#include <hip/hip_runtime.h>

using s8 = __attribute__((ext_vector_type(8))) short;
using f4 = __attribute__((ext_vector_type(4))) float;

constexpr int WIDTH   = 16;
constexpr int HID     = 512;
constexpr int NHEADS  = 8;
constexpr int DK      = 64;
constexpr int NLAYERS = 2;
constexpr int NHW     = 2;
constexpr int B       = 4;
constexpr int S       = 1024;
constexpr int PAD     = S + 2 * WIDTH;   // 1056
constexpr int K2      = 3 * HID;         // 1536 split-K; acts=[H|L|H], wts=[H|H|L]

// ---------------------------------------------------------------------------
// bf16 split helpers. acts layout [H|L|H], weights layout [H|H|L] so the
// K2-dot gives Ah*Bh + Al*Bh + Ah*Bl  (drops only Al*Bl ~ 2^-18).
// ---------------------------------------------------------------------------
__device__ inline unsigned short f2bf(float x) {
    union { float f; unsigned u; } c; c.f = x;
    unsigned r = c.u + 0x7fffu + ((c.u >> 16) & 1u);
    return (unsigned short)(r >> 16);
}
__device__ inline float bf2f(unsigned short h) {
    union { float f; unsigned u; } c; c.u = ((unsigned)h) << 16; return c.f;
}
__device__ inline void split2(float x, unsigned short& h, unsigned short& l) {
    h = f2bf(x);
    l = f2bf(x - bf2f(h));
}
__device__ inline void pack_hl(float4 v, uint2& hp, uint2& lp) {
    unsigned short h[4], l[4];
    split2(v.x, h[0], l[0]); split2(v.y, h[1], l[1]);
    split2(v.z, h[2], l[2]); split2(v.w, h[3], l[3]);
    hp.x = h[0] | ((unsigned)h[1] << 16); hp.y = h[2] | ((unsigned)h[3] << 16);
    lp.x = l[0] | ((unsigned)l[1] << 16); lp.y = l[2] | ((unsigned)l[3] << 16);
}
// activations: [H | L | H]
__device__ inline void store_split4_a(unsigned short* dst, float4 v) {
    uint2 hp, lp; pack_hl(v, hp, lp);
    *(uint2*)(dst)           = hp;
    *(uint2*)(dst + HID)     = lp;
    *(uint2*)(dst + 2 * HID) = hp;
}
// weights: [H | H | L]   <-- R2 bug: this was [H|L|H], doubling Ah*Bh
__device__ inline void store_split4_w(unsigned short* dst, float4 v) {
    uint2 hp, lp; pack_hl(v, hp, lp);
    *(uint2*)(dst)           = hp;
    *(uint2*)(dst + HID)     = hp;
    *(uint2*)(dst + 2 * HID) = lp;
}

// ---------------------------------------------------------------------------
// build padded sequence directly as split acts [B*PAD, K2]
// ---------------------------------------------------------------------------
__global__ __launch_bounds__(256) void build_pad_split(
    const float* __restrict__ x,      // [B, S, HID]
    const float* __restrict__ front,  // [WIDTH, HID]
    const float* __restrict__ back,   // [WIDTH, HID]
    unsigned short* __restrict__ xp2) // [B*PAD, K2]
{
    int idx = blockIdx.x * 256 + threadIdx.x;   // over B*PAD*128
    int c4 = idx & 127;
    int rest = idx >> 7;
    int p = rest % PAD;
    int b = rest / PAD;
    float4 val;
    if (p < WIDTH) {
        val = *(const float4*)(front + (size_t)p * HID + c4 * 4);
    } else if (p < WIDTH + S) {
        val = *(const float4*)(x + ((size_t)b * S + (p - WIDTH)) * HID + c4 * 4);
    } else {
        val = *(const float4*)(back + (size_t)(p - WIDTH - S) * HID + c4 * 4);
    }
    store_split4_a(xp2 + (size_t)(b * PAD + p) * K2 + c4 * 4, val);
}

// ---------------------------------------------------------------------------
// weight rows fp32 [R, HID] -> split bf16 [R, K2] (weights layout)
// ---------------------------------------------------------------------------
__global__ __launch_bounds__(256) void conv_w(
    const float* __restrict__ src, unsigned short* __restrict__ dst)
{
    int idx = blockIdx.x * 256 + threadIdx.x;   // over R*128
    int c4 = idx & 127;
    int r  = idx >> 7;
    float4 v = *(const float4*)(src + (size_t)r * HID + c4 * 4);
    store_split4_w(dst + (size_t)r * K2 + c4 * 4, v);
}

// ---------------------------------------------------------------------------
// Split-bf16 MFMA GEMM (NT): C[M,N] = A''[M,K2] * B''[N,K2]^T + bias[N]
// 128x128 tile, BK=32, global_load_lds 16B staging, 16x16x32 bf16 MFMA.
// ---------------------------------------------------------------------------
__global__ __launch_bounds__(256) void gemm_split(
    const unsigned short* __restrict__ A,
    const unsigned short* __restrict__ Bw,
    const float* __restrict__ bias,
    float* __restrict__ C, int M, int N)
{
    __shared__ unsigned short Als[128 * 32];
    __shared__ unsigned short Bls[128 * 32];

    const int tid  = threadIdx.x;
    const int wave = tid >> 6;
    const int lane = tid & 63;
    const int bm = blockIdx.y * 128;
    const int bn = blockIdx.x * 128;
    const int wm = (wave >> 1) * 64;
    const int wn = (wave & 1) * 64;

    const int c0 = wave * 2, c1 = wave * 2 + 1;
    const int sr0 = c0 * 16 + (lane >> 2);
    const int sr1 = c1 * 16 + (lane >> 2);
    const int sc  = (lane & 3) * 8;
    const unsigned short* Ag0 = A  + (size_t)(bm + sr0) * K2 + sc;
    const unsigned short* Ag1 = A  + (size_t)(bm + sr1) * K2 + sc;
    const unsigned short* Bg0 = Bw + (size_t)(bn + sr0) * K2 + sc;
    const unsigned short* Bg1 = Bw + (size_t)(bn + sr1) * K2 + sc;

    f4 acc[4][4] = {};

    for (int k0 = 0; k0 < K2; k0 += 32) {
        __builtin_amdgcn_global_load_lds(
            (const __attribute__((address_space(1))) void*)(Ag0 + k0),
            (__attribute__((address_space(3))) void*)&Als[c0 * 512], 16, 0, 0);
        __builtin_amdgcn_global_load_lds(
            (const __attribute__((address_space(1))) void*)(Ag1 + k0),
            (__attribute__((address_space(3))) void*)&Als[c1 * 512], 16, 0, 0);
        __builtin_amdgcn_global_load_lds(
            (const __attribute__((address_space(1))) void*)(Bg0 + k0),
            (__attribute__((address_space(3))) void*)&Bls[c0 * 512], 16, 0, 0);
        __builtin_amdgcn_global_load_lds(
            (const __attribute__((address_space(1))) void*)(Bg1 + k0),
            (__attribute__((address_space(3))) void*)&Bls[c1 * 512], 16, 0, 0);
        __syncthreads();

        const int fr = lane & 15;
        const int fk = (lane >> 4) * 8;
        s8 a[4], b[4];
        #pragma unroll
        for (int i = 0; i < 4; ++i)
            a[i] = *(const s8*)&Als[(wm + i * 16 + fr) * 32 + fk];
        #pragma unroll
        for (int j = 0; j < 4; ++j)
            b[j] = *(const s8*)&Bls[(wn + j * 16 + fr) * 32 + fk];
        #pragma unroll
        for (int i = 0; i < 4; ++i)
            #pragma unroll
            for (int j = 0; j < 4; ++j)
                acc[i][j] = __builtin_amdgcn_mfma_f32_16x16x32_bf16(
                    a[i], b[j], acc[i][j], 0, 0, 0);
        __syncthreads();
    }

    const int col = lane & 15;
    const int rb  = (lane >> 4) * 4;
    #pragma unroll
    for (int j = 0; j < 4; ++j) {
        float bj = bias[bn + wn + j * 16 + col];
        #pragma unroll
        for (int i = 0; i < 4; ++i) {
            size_t base = (size_t)(bm + wm + i * 16 + rb) * N + (bn + wn + j * 16 + col);
            #pragma unroll
            for (int r = 0; r < 4; ++r)
                C[base + (size_t)r * N] = acc[i][j][r] + bj;
        }
    }
}

// ---------------------------------------------------------------------------
// Banded MHA on fused QKV [B*PAD, 1536] (q|k|v); writes split acts [B*PAD,K2]
// ---------------------------------------------------------------------------
__global__ __launch_bounds__(256) void banded_attn(
    const float* __restrict__ QKV,
    unsigned short* __restrict__ O2,
    int backward)
{
    int w    = blockIdx.x * 4 + (threadIdx.x >> 6);
    int lane = threadIdx.x & 63;
    int i  = w % PAD;
    int bh = w / PAD;
    int h  = bh & (NHEADS - 1);
    int b  = bh / NHEADS;

    int jlo, jhi;
    if (backward) {
        jlo = i;
        jhi = i + WIDTH + 1; if (jhi > PAD - 1) jhi = PAD - 1;
    } else {
        jlo = i - WIDTH - 1; if (jlo < 0) jlo = 0;
        jhi = i;
    }
    int n = jhi - jlo + 1;

    int col = h * DK + lane;
    float qd = QKV[(size_t)(b * PAD + i) * 1536 + col];

    float sc[WIDTH + 2];
    for (int t = 0; t < n; ++t) {
        float p = qd * QKV[(size_t)(b * PAD + jlo + t) * 1536 + 512 + col];
        #pragma unroll
        for (int off = 32; off > 0; off >>= 1) p += __shfl_xor(p, off);
        sc[t] = p * 0.125f;
    }
    float m = -1e30f;
    for (int t = 0; t < n; ++t) m = fmaxf(m, sc[t]);
    float denom = 0.f;
    for (int t = 0; t < n; ++t) { sc[t] = __expf(sc[t] - m); denom += sc[t]; }
    float inv = 1.0f / denom;
    float od = 0.f;
    for (int t = 0; t < n; ++t)
        od += sc[t] * QKV[(size_t)(b * PAD + jlo + t) * 1536 + 1024 + col];
    od *= inv;

    unsigned short hh, ll;
    split2(od, hh, ll);
    size_t ro = (size_t)(b * PAD + i) * K2 + col;
    O2[ro] = hh; O2[ro + HID] = ll; O2[ro + 2 * HID] = hh;
}

// ---------------------------------------------------------------------------
// rel combine -> split acts only (the fp32 copy is reconstructed by the gate)
// ---------------------------------------------------------------------------
__global__ __launch_bounds__(256) void rel_combine(
    const float* __restrict__ att,     // [B*PAD, HID]
    const float* __restrict__ w,       // [WIDTH+1]
    unsigned short* __restrict__ fo2,  // [B*S rows of K2]
    int offset)
{
    int idx = blockIdx.x * 256 + threadIdx.x;   // over B*S*128
    int c4 = idx & 127;
    int rest = idx >> 7;
    int t = rest & (S - 1);
    int b = rest >> 10;

    const float* rowbase = att + (size_t)b * PAD * HID + c4 * 4;
    float4 acc = *(const float4*)(rowbase + (size_t)(WIDTH + t) * HID);
    #pragma unroll
    for (int k = 0; k <= WIDTH; ++k) {
        float wk = w[k];
        float4 xv = *(const float4*)(rowbase + (size_t)(offset + k + t) * HID);
        acc.x += wk * xv.x; acc.y += wk * xv.y;
        acc.z += wk * xv.z; acc.w += wk * xv.w;
    }
    store_split4_a(fo2 + ((size_t)b * S + t) * K2 + c4 * 4, acc);
}

// ---------------------------------------------------------------------------
// highway gate; x reconstructed from split acts (h+l). Writes split (i=0)
// or fp32 dst (i=1).
// ---------------------------------------------------------------------------
__global__ __launch_bounds__(256) void highway_gate(
    const unsigned short* __restrict__ x2,  // [rows, K2] split acts
    const float* __restrict__ proj,         // [rows, 2*HID]
    float* __restrict__ outf,               // fp32 dst or nullptr
    unsigned short* __restrict__ out2)      // split dst (may ==x2) or nullptr
{
    int idx = blockIdx.x * 256 + threadIdx.x;   // over B*S*128
    int c4 = idx & 127;
    int r  = idx >> 7;
    const unsigned short* xr = x2 + (size_t)r * K2 + c4 * 4;
    uint2 hp = *(const uint2*)(xr);
    uint2 lp = *(const uint2*)(xr + HID);
    float4 xv;
    xv.x = bf2f((unsigned short)(hp.x & 0xffff)) + bf2f((unsigned short)(lp.x & 0xffff));
    xv.y = bf2f((unsigned short)(hp.x >> 16))    + bf2f((unsigned short)(lp.x >> 16));
    xv.z = bf2f((unsigned short)(hp.y & 0xffff)) + bf2f((unsigned short)(lp.y & 0xffff));
    xv.w = bf2f((unsigned short)(hp.y >> 16))    + bf2f((unsigned short)(lp.y >> 16));

    float4 nl = *(const float4*)(proj + (size_t)r * (2 * HID) + c4 * 4);
    float4 g  = *(const float4*)(proj + (size_t)r * (2 * HID) + HID + c4 * 4);
    float4 o;
    float sg;
    sg = 1.f / (1.f + __expf(-g.x)); o.x = sg * xv.x + (1.f - sg) * fmaxf(nl.x, 0.f);
    sg = 1.f / (1.f + __expf(-g.y)); o.y = sg * xv.y + (1.f - sg) * fmaxf(nl.y, 0.f);
    sg = 1.f / (1.f + __expf(-g.z)); o.z = sg * xv.z + (1.f - sg) * fmaxf(nl.z, 0.f);
    sg = 1.f / (1.f + __expf(-g.w)); o.w = sg * xv.w + (1.f - sg) * fmaxf(nl.w, 0.f);
    if (outf) *(float4*)(outf + (size_t)idx * 4) = o;
    if (out2) store_split4_a(out2 + (size_t)r * K2 + c4 * 4, o);
}

// ---------------------------------------------------------------------------
__global__ __launch_bounds__(256) void write_out(
    const float* __restrict__ f, const float* __restrict__ bk,
    float* __restrict__ out)
{
    int idx = blockIdx.x * 256 + threadIdx.x;   // over B*S*256
    int c4 = idx & 255;
    int r  = idx >> 8;
    float4 v;
    if (c4 < 128) v = *(const float4*)(f  + (size_t)r * HID + c4 * 4);
    else          v = *(const float4*)(bk + (size_t)r * HID + (c4 - 128) * 4);
    *(float4*)(out + (size_t)r * (2 * HID) + c4 * 4) = v;
}

// ---------------------------------------------------------------------------
extern "C" void kernel_launch(void* const* d_in, const int* in_sizes, int n_in,
                              void* d_out, int out_size, void* d_ws, size_t ws_size,
                              hipStream_t stream)
{
    const float* inputs   = (const float*)d_in[0];
    const float* fw_lin_w = (const float*)d_in[2];
    const float* fw_lin_b = (const float*)d_in[3];
    const float* bw_lin_w = (const float*)d_in[4];
    const float* bw_lin_b = (const float*)d_in[5];
    const float* fw_hw_w  = (const float*)d_in[6];
    const float* fw_hw_b  = (const float*)d_in[7];
    const float* bw_hw_w  = (const float*)d_in[8];
    const float* bw_hw_b  = (const float*)d_in[9];
    const float* fw_pad   = (const float*)d_in[10];
    const float* bw_pad   = (const float*)d_in[11];
    const float* fw_rel   = (const float*)d_in[12];
    const float* bw_rel   = (const float*)d_in[13];
    float* out = (float*)d_out;
    float* ws  = (float*)d_ws;

    const size_t BSH = (size_t)B * S * HID;     // 2,097,152
    const int MP = B * PAD;                     // 4224
    const int MS = B * S;                       // 4096

    // ws budget (floats-equiv): 2*BSH + MP*1536 + act2/2 + w2/2 = 15,106,048
    // = 60.42 MB total (round-1-proven footprint level)
    float* f   = ws;                            // [B*S, HID]
    float* bk  = f + BSH;                       // [B*S, HID]
    float* qkv = bk + BSH;                      // [MP, 1536] fp32
    float* att = qkv;                           // [MP, 512]  (alias; qkv dead)
    float* hwp = qkv + (size_t)MP * HID;        // [MS, 1024] (alias qkv tail)
    unsigned short* act2 = (unsigned short*)(qkv + (size_t)MP * 1536); // [MP,K2]
    unsigned short* w2   = act2 + (size_t)MP * K2;                     // [1536,K2]

    for (int l = 0; l < NLAYERS; ++l) {
        for (int dir = 0; dir < 2; ++dir) {
            const float* src   = (l == 0) ? inputs : (dir ? bk : f);
            const float* lin_w = (dir ? bw_lin_w : fw_lin_w) + (size_t)l * 4 * HID * HID;
            const float* lin_b = (dir ? bw_lin_b : fw_lin_b) + (size_t)l * 4 * HID;
            const float* hw_w  = (dir ? bw_hw_w  : fw_hw_w ) + (size_t)l * NHW * 2 * HID * HID;
            const float* hw_b  = (dir ? bw_hw_b  : fw_hw_b ) + (size_t)l * NHW * 2 * HID;
            const float* relw  = (dir ? bw_rel   : fw_rel  ) + (size_t)l * (WIDTH + 1);
            const float* front = fw_pad + (size_t)l * WIDTH * HID;
            const float* back  = bw_pad + (size_t)l * WIDTH * HID;
            float* dst = dir ? bk : f;

            build_pad_split<<<MP * 128 / 256, 256, 0, stream>>>(src, front, back, act2);

            conv_w<<<1536 * 128 / 256, 256, 0, stream>>>(lin_w, w2);
            gemm_split<<<dim3(1536 / 128, MP / 128), 256, 0, stream>>>(
                act2, w2, lin_b, qkv, MP, 1536);

            banded_attn<<<(B * NHEADS * PAD) / 4, 256, 0, stream>>>(qkv, act2, dir);

            conv_w<<<512 * 128 / 256, 256, 0, stream>>>(lin_w + 3 * (size_t)HID * HID, w2);
            gemm_split<<<dim3(512 / 128, MP / 128), 256, 0, stream>>>(
                act2, w2, lin_b + 3 * HID, att, MP, 512);

            rel_combine<<<MS * 128 / 256, 256, 0, stream>>>(
                att, relw, act2, dir ? WIDTH : 0);

            for (int i = 0; i < NHW; ++i) {
                conv_w<<<1024 * 128 / 256, 256, 0, stream>>>(
                    hw_w + (size_t)i * 2 * HID * HID, w2);
                gemm_split<<<dim3(1024 / 128, MS / 128), 256, 0, stream>>>(
                    act2, w2, hw_b + (size_t)i * 2 * HID, hwp, MS, 1024);
                highway_gate<<<MS * 128 / 256, 256, 0, stream>>>(
                    act2, hwp,
                    (i == NHW - 1) ? dst : (float*)nullptr,
                    (i == NHW - 1) ? (unsigned short*)nullptr : act2);
            }
        }
        write_out<<<MS * 256 / 256, 256, 0, stream>>>(
            f, bk, out + (size_t)l * B * S * 2 * HID);
    }
}

// Round 4
// 916.020 us; speedup vs baseline: 1.9397x; 1.2552x over previous
//
#include <hip/hip_runtime.h>

using s8 = __attribute__((ext_vector_type(8))) short;
using f4 = __attribute__((ext_vector_type(4))) float;

constexpr int WIDTH   = 16;
constexpr int HID     = 512;
constexpr int NHEADS  = 8;
constexpr int DK      = 64;
constexpr int NLAYERS = 2;
constexpr int NHW     = 2;
constexpr int B       = 4;
constexpr int S       = 1024;
constexpr int PAD     = S + 2 * WIDTH;   // 1056
constexpr int K2      = 3 * HID;         // 1536 split-K; acts=[H|L|H], wts=[H|H|L]

// ---------------------------------------------------------------------------
// bf16 split helpers. acts layout [H|L|H], weights layout [H|H|L] so the
// K2-dot gives Ah*Bh + Al*Bh + Ah*Bl  (drops only Al*Bl ~ 2^-18).
// ---------------------------------------------------------------------------
__device__ inline unsigned short f2bf(float x) {
    union { float f; unsigned u; } c; c.f = x;
    unsigned r = c.u + 0x7fffu + ((c.u >> 16) & 1u);
    return (unsigned short)(r >> 16);
}
__device__ inline float bf2f(unsigned short h) {
    union { float f; unsigned u; } c; c.u = ((unsigned)h) << 16; return c.f;
}
__device__ inline void split2(float x, unsigned short& h, unsigned short& l) {
    h = f2bf(x);
    l = f2bf(x - bf2f(h));
}
__device__ inline void pack_hl(float4 v, uint2& hp, uint2& lp) {
    unsigned short h[4], l[4];
    split2(v.x, h[0], l[0]); split2(v.y, h[1], l[1]);
    split2(v.z, h[2], l[2]); split2(v.w, h[3], l[3]);
    hp.x = h[0] | ((unsigned)h[1] << 16); hp.y = h[2] | ((unsigned)h[3] << 16);
    lp.x = l[0] | ((unsigned)l[1] << 16); lp.y = l[2] | ((unsigned)l[3] << 16);
}
// activations: [H | L | H]
__device__ inline void store_split4_a(unsigned short* dst, float4 v) {
    uint2 hp, lp; pack_hl(v, hp, lp);
    *(uint2*)(dst)           = hp;
    *(uint2*)(dst + HID)     = lp;
    *(uint2*)(dst + 2 * HID) = hp;
}
// weights: [H | H | L]
__device__ inline void store_split4_w(unsigned short* dst, float4 v) {
    uint2 hp, lp; pack_hl(v, hp, lp);
    *(uint2*)(dst)           = hp;
    *(uint2*)(dst + HID)     = hp;
    *(uint2*)(dst + 2 * HID) = lp;
}

// ---------------------------------------------------------------------------
// build padded sequence directly as split acts [B*PAD, K2]
// ---------------------------------------------------------------------------
__global__ __launch_bounds__(256) void build_pad_split(
    const float* __restrict__ x,      // [B, S, HID]
    const float* __restrict__ front,  // [WIDTH, HID]
    const float* __restrict__ back,   // [WIDTH, HID]
    unsigned short* __restrict__ xp2) // [B*PAD, K2]
{
    int idx = blockIdx.x * 256 + threadIdx.x;   // over B*PAD*128
    int c4 = idx & 127;
    int rest = idx >> 7;
    int p = rest % PAD;
    int b = rest / PAD;
    float4 val;
    if (p < WIDTH) {
        val = *(const float4*)(front + (size_t)p * HID + c4 * 4);
    } else if (p < WIDTH + S) {
        val = *(const float4*)(x + ((size_t)b * S + (p - WIDTH)) * HID + c4 * 4);
    } else {
        val = *(const float4*)(back + (size_t)(p - WIDTH - S) * HID + c4 * 4);
    }
    store_split4_a(xp2 + (size_t)(b * PAD + p) * K2 + c4 * 4, val);
}

// ---------------------------------------------------------------------------
// weight rows fp32 [R, HID] -> split bf16 [R, K2] (weights layout)
// ---------------------------------------------------------------------------
__global__ __launch_bounds__(256) void conv_w(
    const float* __restrict__ src, unsigned short* __restrict__ dst)
{
    int idx = blockIdx.x * 256 + threadIdx.x;   // over R*128
    int c4 = idx & 127;
    int r  = idx >> 7;
    float4 v = *(const float4*)(src + (size_t)r * HID + c4 * 4);
    store_split4_w(dst + (size_t)r * K2 + c4 * 4, v);
}

// ---------------------------------------------------------------------------
// Split-bf16 MFMA GEMM (NT): C[M,N] = A''[M,K2] * B''[N,K2]^T + bias[N]
// 128x128 tile, BK=32, global_load_lds 16B staging, 16x16x32 bf16 MFMA.
// ---------------------------------------------------------------------------
__global__ __launch_bounds__(256) void gemm_split(
    const unsigned short* __restrict__ A,
    const unsigned short* __restrict__ Bw,
    const float* __restrict__ bias,
    float* __restrict__ C, int M, int N)
{
    __shared__ unsigned short Als[128 * 32];
    __shared__ unsigned short Bls[128 * 32];

    const int tid  = threadIdx.x;
    const int wave = tid >> 6;
    const int lane = tid & 63;
    const int bm = blockIdx.y * 128;
    const int bn = blockIdx.x * 128;
    const int wm = (wave >> 1) * 64;
    const int wn = (wave & 1) * 64;

    const int c0 = wave * 2, c1 = wave * 2 + 1;
    const int sr0 = c0 * 16 + (lane >> 2);
    const int sr1 = c1 * 16 + (lane >> 2);
    const int sc  = (lane & 3) * 8;
    const unsigned short* Ag0 = A  + (size_t)(bm + sr0) * K2 + sc;
    const unsigned short* Ag1 = A  + (size_t)(bm + sr1) * K2 + sc;
    const unsigned short* Bg0 = Bw + (size_t)(bn + sr0) * K2 + sc;
    const unsigned short* Bg1 = Bw + (size_t)(bn + sr1) * K2 + sc;

    f4 acc[4][4] = {};

    for (int k0 = 0; k0 < K2; k0 += 32) {
        __builtin_amdgcn_global_load_lds(
            (const __attribute__((address_space(1))) void*)(Ag0 + k0),
            (__attribute__((address_space(3))) void*)&Als[c0 * 512], 16, 0, 0);
        __builtin_amdgcn_global_load_lds(
            (const __attribute__((address_space(1))) void*)(Ag1 + k0),
            (__attribute__((address_space(3))) void*)&Als[c1 * 512], 16, 0, 0);
        __builtin_amdgcn_global_load_lds(
            (const __attribute__((address_space(1))) void*)(Bg0 + k0),
            (__attribute__((address_space(3))) void*)&Bls[c0 * 512], 16, 0, 0);
        __builtin_amdgcn_global_load_lds(
            (const __attribute__((address_space(1))) void*)(Bg1 + k0),
            (__attribute__((address_space(3))) void*)&Bls[c1 * 512], 16, 0, 0);
        __syncthreads();

        const int fr = lane & 15;
        const int fk = (lane >> 4) * 8;
        s8 a[4], b[4];
        #pragma unroll
        for (int i = 0; i < 4; ++i)
            a[i] = *(const s8*)&Als[(wm + i * 16 + fr) * 32 + fk];
        #pragma unroll
        for (int j = 0; j < 4; ++j)
            b[j] = *(const s8*)&Bls[(wn + j * 16 + fr) * 32 + fk];
        #pragma unroll
        for (int i = 0; i < 4; ++i)
            #pragma unroll
            for (int j = 0; j < 4; ++j)
                acc[i][j] = __builtin_amdgcn_mfma_f32_16x16x32_bf16(
                    a[i], b[j], acc[i][j], 0, 0, 0);
        __syncthreads();
    }

    const int col = lane & 15;
    const int rb  = (lane >> 4) * 4;
    #pragma unroll
    for (int j = 0; j < 4; ++j) {
        float bj = bias[bn + wn + j * 16 + col];
        #pragma unroll
        for (int i = 0; i < 4; ++i) {
            size_t base = (size_t)(bm + wm + i * 16 + rb) * N + (bn + wn + j * 16 + col);
            #pragma unroll
            for (int r = 0; r < 4; ++r)
                C[base + (size_t)r * N] = acc[i][j][r] + bj;
        }
    }
}

// ---------------------------------------------------------------------------
// Banded MHA v2. One wave per (b,h,i).
// QK: lane=(s,d): 4 taps in parallel, float4 dots, 4-level butterfly in 16.
// Softmax: static shfl broadcasts; t>=n masked to -1e30 (exp -> exactly 0).
// PV: lane=dk, out-of-band taps clamped (weight 0).
// ---------------------------------------------------------------------------
__global__ __launch_bounds__(256) void banded_attn(
    const float* __restrict__ QKV,    // [B*PAD, 1536] (q|k|v)
    unsigned short* __restrict__ O2,  // split acts [B*PAD, K2]
    int backward)
{
    int w    = blockIdx.x * 4 + (threadIdx.x >> 6);
    int lane = threadIdx.x & 63;
    int i  = w % PAD;
    int bh = w / PAD;
    int h  = bh & (NHEADS - 1);
    int b  = bh / NHEADS;

    int jlo, n;
    if (backward) { jlo = i; n = min(WIDTH + 2, PAD - i); }
    else          { jlo = max(0, i - WIDTH - 1); n = i - jlo + 1; }

    const int s = lane >> 4;      // tap subgroup 0..3
    const int d = lane & 15;      // dk quad 0..15
    const size_t rowbase = (size_t)(b * PAD) * 1536;
    const int colq = h * DK;

    float4 q4 = *(const float4*)(QKV + rowbase + (size_t)i * 1536 + colq + 4 * d);

    float sc[5];
    #pragma unroll
    for (int m = 0; m < 5; ++m) {
        int t  = 4 * m + s;
        int tc = t < n ? t : n - 1;
        float4 kv = *(const float4*)(QKV + rowbase + (size_t)(jlo + tc) * 1536
                                     + 512 + colq + 4 * d);
        float p = q4.x * kv.x + q4.y * kv.y + q4.z * kv.z + q4.w * kv.w;
        p += __shfl_xor(p, 1);
        p += __shfl_xor(p, 2);
        p += __shfl_xor(p, 4);
        p += __shfl_xor(p, 8);
        sc[m] = p * 0.125f;     // 1/sqrt(64)
    }

    // gather all 18 scores to every lane (tap t held by subgroup t&3)
    float sv[WIDTH + 2];
    #pragma unroll
    for (int t = 0; t < WIDTH + 2; ++t) {
        float v = __shfl(sc[t >> 2], (t & 3) << 4);
        sv[t] = (t < n) ? v : -1e30f;
    }
    float mx = sv[0];
    #pragma unroll
    for (int t = 1; t < WIDTH + 2; ++t) mx = fmaxf(mx, sv[t]);
    float denom = 0.f;
    #pragma unroll
    for (int t = 0; t < WIDTH + 2; ++t) { sv[t] = __expf(sv[t] - mx); denom += sv[t]; }
    float inv = 1.0f / denom;

    // PV: lane = dk
    float od0 = 0.f, od1 = 0.f;
    #pragma unroll
    for (int t = 0; t < WIDTH + 2; t += 2) {
        int tc0 = t     < n ? t     : n - 1;
        int tc1 = t + 1 < n ? t + 1 : n - 1;
        od0 += sv[t]     * QKV[rowbase + (size_t)(jlo + tc0) * 1536 + 1024 + colq + lane];
        od1 += sv[t + 1] * QKV[rowbase + (size_t)(jlo + tc1) * 1536 + 1024 + colq + lane];
    }
    float od = (od0 + od1) * inv;

    unsigned short hh, ll;
    split2(od, hh, ll);
    size_t ro = (size_t)(b * PAD + i) * K2 + colq + lane;
    O2[ro] = hh; O2[ro + HID] = ll; O2[ro + 2 * HID] = hh;
}

// ---------------------------------------------------------------------------
// rel combine -> split acts only
// ---------------------------------------------------------------------------
__global__ __launch_bounds__(256) void rel_combine(
    const float* __restrict__ att,     // [B*PAD, HID]
    const float* __restrict__ w,       // [WIDTH+1]
    unsigned short* __restrict__ fo2,  // [B*S rows of K2]
    int offset)
{
    int idx = blockIdx.x * 256 + threadIdx.x;   // over B*S*128
    int c4 = idx & 127;
    int rest = idx >> 7;
    int t = rest & (S - 1);
    int b = rest >> 10;

    const float* rowbase = att + (size_t)b * PAD * HID + c4 * 4;
    float4 acc = *(const float4*)(rowbase + (size_t)(WIDTH + t) * HID);
    #pragma unroll
    for (int k = 0; k <= WIDTH; ++k) {
        float wk = w[k];
        float4 xv = *(const float4*)(rowbase + (size_t)(offset + k + t) * HID);
        acc.x += wk * xv.x; acc.y += wk * xv.y;
        acc.z += wk * xv.z; acc.w += wk * xv.w;
    }
    store_split4_a(fo2 + ((size_t)b * S + t) * K2 + c4 * 4, acc);
}

// ---------------------------------------------------------------------------
// highway gate; x reconstructed from split acts (h+l).
// i=0: writes split acts. i=1: writes fp32 dst AND the final output slice.
// ---------------------------------------------------------------------------
__global__ __launch_bounds__(256) void highway_gate(
    const unsigned short* __restrict__ x2,  // [rows, K2] split acts
    const float* __restrict__ proj,         // [rows, 2*HID]
    float* __restrict__ outf,               // fp32 dst or nullptr
    unsigned short* __restrict__ out2,      // split dst (may ==x2) or nullptr
    float* __restrict__ oslice)             // out + l*.. + dir*HID, stride 2*HID
{
    int idx = blockIdx.x * 256 + threadIdx.x;   // over B*S*128
    int c4 = idx & 127;
    int r  = idx >> 7;
    const unsigned short* xr = x2 + (size_t)r * K2 + c4 * 4;
    uint2 hp = *(const uint2*)(xr);
    uint2 lp = *(const uint2*)(xr + HID);
    float4 xv;
    xv.x = bf2f((unsigned short)(hp.x & 0xffff)) + bf2f((unsigned short)(lp.x & 0xffff));
    xv.y = bf2f((unsigned short)(hp.x >> 16))    + bf2f((unsigned short)(lp.x >> 16));
    xv.z = bf2f((unsigned short)(hp.y & 0xffff)) + bf2f((unsigned short)(lp.y & 0xffff));
    xv.w = bf2f((unsigned short)(hp.y >> 16))    + bf2f((unsigned short)(lp.y >> 16));

    float4 nl = *(const float4*)(proj + (size_t)r * (2 * HID) + c4 * 4);
    float4 g  = *(const float4*)(proj + (size_t)r * (2 * HID) + HID + c4 * 4);
    float4 o;
    float sg;
    sg = 1.f / (1.f + __expf(-g.x)); o.x = sg * xv.x + (1.f - sg) * fmaxf(nl.x, 0.f);
    sg = 1.f / (1.f + __expf(-g.y)); o.y = sg * xv.y + (1.f - sg) * fmaxf(nl.y, 0.f);
    sg = 1.f / (1.f + __expf(-g.z)); o.z = sg * xv.z + (1.f - sg) * fmaxf(nl.z, 0.f);
    sg = 1.f / (1.f + __expf(-g.w)); o.w = sg * xv.w + (1.f - sg) * fmaxf(nl.w, 0.f);
    if (outf)   *(float4*)(outf + (size_t)idx * 4) = o;
    if (out2)   store_split4_a(out2 + (size_t)r * K2 + c4 * 4, o);
    if (oslice) *(float4*)(oslice + (size_t)r * (2 * HID) + c4 * 4) = o;
}

// ---------------------------------------------------------------------------
extern "C" void kernel_launch(void* const* d_in, const int* in_sizes, int n_in,
                              void* d_out, int out_size, void* d_ws, size_t ws_size,
                              hipStream_t stream)
{
    const float* inputs   = (const float*)d_in[0];
    const float* fw_lin_w = (const float*)d_in[2];
    const float* fw_lin_b = (const float*)d_in[3];
    const float* bw_lin_w = (const float*)d_in[4];
    const float* bw_lin_b = (const float*)d_in[5];
    const float* fw_hw_w  = (const float*)d_in[6];
    const float* fw_hw_b  = (const float*)d_in[7];
    const float* bw_hw_w  = (const float*)d_in[8];
    const float* bw_hw_b  = (const float*)d_in[9];
    const float* fw_pad   = (const float*)d_in[10];
    const float* bw_pad   = (const float*)d_in[11];
    const float* fw_rel   = (const float*)d_in[12];
    const float* bw_rel   = (const float*)d_in[13];
    float* out = (float*)d_out;
    float* ws  = (float*)d_ws;

    const size_t BSH = (size_t)B * S * HID;     // 2,097,152
    const int MP = B * PAD;                     // 4224
    const int MS = B * S;                       // 4096

    float* f   = ws;                            // [B*S, HID]
    float* bk  = f + BSH;                       // [B*S, HID]
    float* qkv = bk + BSH;                      // [MP, 1536] fp32
    float* att = qkv;                           // [MP, 512]  (alias; qkv dead)
    float* hwp = qkv + (size_t)MP * HID;        // [MS, 1024] (alias qkv tail)
    unsigned short* act2 = (unsigned short*)(qkv + (size_t)MP * 1536); // [MP,K2]
    unsigned short* w2   = act2 + (size_t)MP * K2;                     // [1536,K2]

    for (int l = 0; l < NLAYERS; ++l) {
        for (int dir = 0; dir < 2; ++dir) {
            const float* src   = (l == 0) ? inputs : (dir ? bk : f);
            const float* lin_w = (dir ? bw_lin_w : fw_lin_w) + (size_t)l * 4 * HID * HID;
            const float* lin_b = (dir ? bw_lin_b : fw_lin_b) + (size_t)l * 4 * HID;
            const float* hw_w  = (dir ? bw_hw_w  : fw_hw_w ) + (size_t)l * NHW * 2 * HID * HID;
            const float* hw_b  = (dir ? bw_hw_b  : fw_hw_b ) + (size_t)l * NHW * 2 * HID;
            const float* relw  = (dir ? bw_rel   : fw_rel  ) + (size_t)l * (WIDTH + 1);
            const float* front = fw_pad + (size_t)l * WIDTH * HID;
            const float* back  = bw_pad + (size_t)l * WIDTH * HID;
            float* dst = dir ? bk : f;
            float* oslice = out + (size_t)l * B * S * 2 * HID + dir * HID;

            build_pad_split<<<MP * 128 / 256, 256, 0, stream>>>(src, front, back, act2);

            conv_w<<<1536 * 128 / 256, 256, 0, stream>>>(lin_w, w2);
            gemm_split<<<dim3(1536 / 128, MP / 128), 256, 0, stream>>>(
                act2, w2, lin_b, qkv, MP, 1536);

            banded_attn<<<(B * NHEADS * PAD) / 4, 256, 0, stream>>>(qkv, act2, dir);

            conv_w<<<512 * 128 / 256, 256, 0, stream>>>(lin_w + 3 * (size_t)HID * HID, w2);
            gemm_split<<<dim3(512 / 128, MP / 128), 256, 0, stream>>>(
                act2, w2, lin_b + 3 * HID, att, MP, 512);

            rel_combine<<<MS * 128 / 256, 256, 0, stream>>>(
                att, relw, act2, dir ? WIDTH : 0);

            for (int i = 0; i < NHW; ++i) {
                conv_w<<<1024 * 128 / 256, 256, 0, stream>>>(
                    hw_w + (size_t)i * 2 * HID * HID, w2);
                gemm_split<<<dim3(1024 / 128, MS / 128), 256, 0, stream>>>(
                    act2, w2, hw_b + (size_t)i * 2 * HID, hwp, MS, 1024);
                highway_gate<<<MS * 128 / 256, 256, 0, stream>>>(
                    act2, hwp,
                    (i == NHW - 1) ? dst : (float*)nullptr,
                    (i == NHW - 1) ? (unsigned short*)nullptr : act2,
                    (i == NHW - 1) ? oslice : (float*)nullptr);
            }
        }
    }
}

// Round 5
// 690.947 us; speedup vs baseline: 2.5715x; 1.3257x over previous
//
#include <hip/hip_runtime.h>

using s8 = __attribute__((ext_vector_type(8))) short;
using f4 = __attribute__((ext_vector_type(4))) float;

constexpr int WIDTH   = 16;
constexpr int HID     = 512;
constexpr int NHEADS  = 8;
constexpr int DK      = 64;
constexpr int NLAYERS = 2;
constexpr int NHW     = 2;
constexpr int B       = 4;
constexpr int S       = 1024;
constexpr int PAD     = S + 2 * WIDTH;   // 1056
constexpr int RS      = 1024;            // split row stride (shorts): [H(512)|L(512)]

// Split-bf16 scheme: x = h + l (both bf16). Storage is 2-plane [H|L] per row.
// The GEMM K-loop (K2=1536) reads A as [H,L,H] and B as [H,H,L] via k0
// remapping, giving Ah*Bh + Al*Bh + Ah*Bl (drops only Al*Bl ~ 2^-18).
__device__ inline unsigned short f2bf(float x) {
    union { float f; unsigned u; } c; c.f = x;
    unsigned r = c.u + 0x7fffu + ((c.u >> 16) & 1u);
    return (unsigned short)(r >> 16);
}
__device__ inline float bf2f(unsigned short h) {
    union { float f; unsigned u; } c; c.u = ((unsigned)h) << 16; return c.f;
}
__device__ inline void split2(float x, unsigned short& h, unsigned short& l) {
    h = f2bf(x);
    l = f2bf(x - bf2f(h));
}
__device__ inline void store_split4(unsigned short* dst, float4 v) {
    unsigned short h[4], l[4];
    split2(v.x, h[0], l[0]); split2(v.y, h[1], l[1]);
    split2(v.z, h[2], l[2]); split2(v.w, h[3], l[3]);
    uint2 hp, lp;
    hp.x = h[0] | ((unsigned)h[1] << 16); hp.y = h[2] | ((unsigned)h[3] << 16);
    lp.x = l[0] | ((unsigned)l[1] << 16); lp.y = l[2] | ((unsigned)l[3] << 16);
    *(uint2*)(dst)       = hp;
    *(uint2*)(dst + 512) = lp;
}

// ---------------------------------------------------------------------------
// build padded sequence -> split acts [B*PAD, RS]; z selects direction slot
// ---------------------------------------------------------------------------
__global__ __launch_bounds__(256) void build_pad_split(
    const float* __restrict__ src0, const float* __restrict__ src1,
    const float* __restrict__ front, const float* __restrict__ back,
    unsigned short* __restrict__ d0, unsigned short* __restrict__ d1)
{
    const float* x = blockIdx.z ? src1 : src0;
    unsigned short* xp2 = blockIdx.z ? d1 : d0;
    int idx = blockIdx.x * 256 + threadIdx.x;   // over B*PAD*128
    int c4 = idx & 127;
    int rest = idx >> 7;
    int p = rest % PAD;
    int b = rest / PAD;
    float4 val;
    if (p < WIDTH) {
        val = *(const float4*)(front + (size_t)p * HID + c4 * 4);
    } else if (p < WIDTH + S) {
        val = *(const float4*)(x + ((size_t)b * S + (p - WIDTH)) * HID + c4 * 4);
    } else {
        val = *(const float4*)(back + (size_t)(p - WIDTH - S) * HID + c4 * 4);
    }
    store_split4(xp2 + (size_t)(b * PAD + p) * RS + c4 * 4, val);
}

// ---------------------------------------------------------------------------
// weights fp32 [R, HID] -> split [R, RS]
// ---------------------------------------------------------------------------
__global__ __launch_bounds__(256) void conv_w(
    const float* __restrict__ s0, const float* __restrict__ s1,
    unsigned short* __restrict__ w0, unsigned short* __restrict__ w1)
{
    const float* src = blockIdx.z ? s1 : s0;
    unsigned short* dst = blockIdx.z ? w1 : w0;
    int idx = blockIdx.x * 256 + threadIdx.x;   // over R*128
    int c4 = idx & 127;
    int r  = idx >> 7;
    float4 v = *(const float4*)(src + (size_t)r * HID + c4 * 4);
    store_split4(dst + (size_t)r * RS + c4 * 4, v);
}

// ---------------------------------------------------------------------------
// Split-bf16 MFMA GEMM (NT): C = A*B^T + bias over virtual K2=1536.
// A segs [H,L,H]: aoff = k0<1024 ? k0 : k0-1024
// B segs [H,H,L]: boff = k0<512  ? k0 : k0-512
// 128x128 tile, BK=32, global_load_lds 16B, 16x16x32 bf16 MFMA.
// ---------------------------------------------------------------------------
__global__ __launch_bounds__(256) void gemm_split(
    const unsigned short* __restrict__ A0, const unsigned short* __restrict__ B0,
    const float* __restrict__ bias0, float* __restrict__ C0,
    const unsigned short* __restrict__ A1, const unsigned short* __restrict__ B1,
    const float* __restrict__ bias1, float* __restrict__ C1,
    int N)
{
    const unsigned short* A  = blockIdx.z ? A1 : A0;
    const unsigned short* Bw = blockIdx.z ? B1 : B0;
    const float* bias        = blockIdx.z ? bias1 : bias0;
    float* C                 = blockIdx.z ? C1 : C0;

    __shared__ unsigned short Als[128 * 32];
    __shared__ unsigned short Bls[128 * 32];

    const int tid  = threadIdx.x;
    const int wave = tid >> 6;
    const int lane = tid & 63;
    const int bm = blockIdx.y * 128;
    const int bn = blockIdx.x * 128;
    const int wm = (wave >> 1) * 64;
    const int wn = (wave & 1) * 64;

    const int c0 = wave * 2, c1 = wave * 2 + 1;
    const int sr0 = c0 * 16 + (lane >> 2);
    const int sr1 = c1 * 16 + (lane >> 2);
    const int sc  = (lane & 3) * 8;
    const unsigned short* Ag0 = A  + (size_t)(bm + sr0) * RS + sc;
    const unsigned short* Ag1 = A  + (size_t)(bm + sr1) * RS + sc;
    const unsigned short* Bg0 = Bw + (size_t)(bn + sr0) * RS + sc;
    const unsigned short* Bg1 = Bw + (size_t)(bn + sr1) * RS + sc;

    f4 acc[4][4] = {};

    for (int k0 = 0; k0 < 1536; k0 += 32) {
        const int aoff = (k0 < 1024) ? k0 : (k0 - 1024);
        const int boff = (k0 < 512)  ? k0 : (k0 - 512);
        __builtin_amdgcn_global_load_lds(
            (const __attribute__((address_space(1))) void*)(Ag0 + aoff),
            (__attribute__((address_space(3))) void*)&Als[c0 * 512], 16, 0, 0);
        __builtin_amdgcn_global_load_lds(
            (const __attribute__((address_space(1))) void*)(Ag1 + aoff),
            (__attribute__((address_space(3))) void*)&Als[c1 * 512], 16, 0, 0);
        __builtin_amdgcn_global_load_lds(
            (const __attribute__((address_space(1))) void*)(Bg0 + boff),
            (__attribute__((address_space(3))) void*)&Bls[c0 * 512], 16, 0, 0);
        __builtin_amdgcn_global_load_lds(
            (const __attribute__((address_space(1))) void*)(Bg1 + boff),
            (__attribute__((address_space(3))) void*)&Bls[c1 * 512], 16, 0, 0);
        __syncthreads();

        const int fr = lane & 15;
        const int fk = (lane >> 4) * 8;
        s8 a[4], b[4];
        #pragma unroll
        for (int i = 0; i < 4; ++i)
            a[i] = *(const s8*)&Als[(wm + i * 16 + fr) * 32 + fk];
        #pragma unroll
        for (int j = 0; j < 4; ++j)
            b[j] = *(const s8*)&Bls[(wn + j * 16 + fr) * 32 + fk];
        #pragma unroll
        for (int i = 0; i < 4; ++i)
            #pragma unroll
            for (int j = 0; j < 4; ++j)
                acc[i][j] = __builtin_amdgcn_mfma_f32_16x16x32_bf16(
                    a[i], b[j], acc[i][j], 0, 0, 0);
        __syncthreads();
    }

    const int col = lane & 15;
    const int rb  = (lane >> 4) * 4;
    #pragma unroll
    for (int j = 0; j < 4; ++j) {
        float bj = bias[bn + wn + j * 16 + col];
        #pragma unroll
        for (int i = 0; i < 4; ++i) {
            size_t base = (size_t)(bm + wm + i * 16 + rb) * N + (bn + wn + j * 16 + col);
            #pragma unroll
            for (int r = 0; r < 4; ++r)
                C[base + (size_t)r * N] = acc[i][j][r] + bj;
        }
    }
}

// ---------------------------------------------------------------------------
// Banded MHA. One wave per (b,h,i). backward = dir0 + z.
// ---------------------------------------------------------------------------
__global__ __launch_bounds__(256) void banded_attn(
    const float* __restrict__ Q0, const float* __restrict__ Q1,
    unsigned short* __restrict__ O0, unsigned short* __restrict__ O1,
    int dir0)
{
    const float* QKV = blockIdx.z ? Q1 : Q0;
    unsigned short* O2 = blockIdx.z ? O1 : O0;
    int backward = dir0 + blockIdx.z;

    int w    = blockIdx.x * 4 + (threadIdx.x >> 6);
    int lane = threadIdx.x & 63;
    int i  = w % PAD;
    int bh = w / PAD;
    int h  = bh & (NHEADS - 1);
    int b  = bh / NHEADS;

    int jlo, n;
    if (backward) { jlo = i; n = min(WIDTH + 2, PAD - i); }
    else          { jlo = max(0, i - WIDTH - 1); n = i - jlo + 1; }

    const int s = lane >> 4;
    const int d = lane & 15;
    const size_t rowbase = (size_t)(b * PAD) * 1536;
    const int colq = h * DK;

    float4 q4 = *(const float4*)(QKV + rowbase + (size_t)i * 1536 + colq + 4 * d);

    float sc[5];
    #pragma unroll
    for (int m = 0; m < 5; ++m) {
        int t  = 4 * m + s;
        int tc = t < n ? t : n - 1;
        float4 kv = *(const float4*)(QKV + rowbase + (size_t)(jlo + tc) * 1536
                                     + 512 + colq + 4 * d);
        float p = q4.x * kv.x + q4.y * kv.y + q4.z * kv.z + q4.w * kv.w;
        p += __shfl_xor(p, 1);
        p += __shfl_xor(p, 2);
        p += __shfl_xor(p, 4);
        p += __shfl_xor(p, 8);
        sc[m] = p * 0.125f;
    }

    float sv[WIDTH + 2];
    #pragma unroll
    for (int t = 0; t < WIDTH + 2; ++t) {
        float v = __shfl(sc[t >> 2], (t & 3) << 4);
        sv[t] = (t < n) ? v : -1e30f;
    }
    float mx = sv[0];
    #pragma unroll
    for (int t = 1; t < WIDTH + 2; ++t) mx = fmaxf(mx, sv[t]);
    float denom = 0.f;
    #pragma unroll
    for (int t = 0; t < WIDTH + 2; ++t) { sv[t] = __expf(sv[t] - mx); denom += sv[t]; }
    float inv = 1.0f / denom;

    float od0 = 0.f, od1 = 0.f;
    #pragma unroll
    for (int t = 0; t < WIDTH + 2; t += 2) {
        int tc0 = t     < n ? t     : n - 1;
        int tc1 = t + 1 < n ? t + 1 : n - 1;
        od0 += sv[t]     * QKV[rowbase + (size_t)(jlo + tc0) * 1536 + 1024 + colq + lane];
        od1 += sv[t + 1] * QKV[rowbase + (size_t)(jlo + tc1) * 1536 + 1024 + colq + lane];
    }
    float od = (od0 + od1) * inv;

    unsigned short hh, ll;
    split2(od, hh, ll);
    size_t ro = (size_t)(b * PAD + i) * RS + colq + lane;
    O2[ro] = hh; O2[ro + 512] = ll;
}

// ---------------------------------------------------------------------------
// rel combine -> split acts
// ---------------------------------------------------------------------------
__global__ __launch_bounds__(256) void rel_combine(
    const float* __restrict__ a0, const float* __restrict__ a1,
    const float* __restrict__ w0, const float* __restrict__ w1,
    unsigned short* __restrict__ f0, unsigned short* __restrict__ f1,
    int off0, int off1)
{
    const float* att = blockIdx.z ? a1 : a0;
    const float* w   = blockIdx.z ? w1 : w0;
    unsigned short* fo2 = blockIdx.z ? f1 : f0;
    int offset = blockIdx.z ? off1 : off0;

    int idx = blockIdx.x * 256 + threadIdx.x;   // over B*S*128
    int c4 = idx & 127;
    int rest = idx >> 7;
    int t = rest & (S - 1);
    int b = rest >> 10;

    const float* rowbase = att + (size_t)b * PAD * HID + c4 * 4;
    float4 acc = *(const float4*)(rowbase + (size_t)(WIDTH + t) * HID);
    #pragma unroll
    for (int k = 0; k <= WIDTH; ++k) {
        float wk = w[k];
        float4 xv = *(const float4*)(rowbase + (size_t)(offset + k + t) * HID);
        acc.x += wk * xv.x; acc.y += wk * xv.y;
        acc.z += wk * xv.z; acc.w += wk * xv.w;
    }
    store_split4(fo2 + ((size_t)b * S + t) * RS + c4 * 4, acc);
}

// ---------------------------------------------------------------------------
// highway gate; x reconstructed from split acts (h+l)
// ---------------------------------------------------------------------------
__global__ __launch_bounds__(256) void highway_gate(
    const unsigned short* __restrict__ x0, const unsigned short* __restrict__ x1,
    const float* __restrict__ p0, const float* __restrict__ p1,
    float* __restrict__ of0, float* __restrict__ of1,
    unsigned short* __restrict__ o20, unsigned short* __restrict__ o21,
    float* __restrict__ os0, float* __restrict__ os1)
{
    const unsigned short* x2 = blockIdx.z ? x1 : x0;
    const float* proj        = blockIdx.z ? p1 : p0;
    float* outf              = blockIdx.z ? of1 : of0;
    unsigned short* out2     = blockIdx.z ? o21 : o20;
    float* oslice            = blockIdx.z ? os1 : os0;

    int idx = blockIdx.x * 256 + threadIdx.x;   // over B*S*128
    int c4 = idx & 127;
    int r  = idx >> 7;
    const unsigned short* xr = x2 + (size_t)r * RS + c4 * 4;
    uint2 hp = *(const uint2*)(xr);
    uint2 lp = *(const uint2*)(xr + 512);
    float4 xv;
    xv.x = bf2f((unsigned short)(hp.x & 0xffff)) + bf2f((unsigned short)(lp.x & 0xffff));
    xv.y = bf2f((unsigned short)(hp.x >> 16))    + bf2f((unsigned short)(lp.x >> 16));
    xv.z = bf2f((unsigned short)(hp.y & 0xffff)) + bf2f((unsigned short)(lp.y & 0xffff));
    xv.w = bf2f((unsigned short)(hp.y >> 16))    + bf2f((unsigned short)(lp.y >> 16));

    float4 nl = *(const float4*)(proj + (size_t)r * (2 * HID) + c4 * 4);
    float4 g  = *(const float4*)(proj + (size_t)r * (2 * HID) + HID + c4 * 4);
    float4 o;
    float sg;
    sg = 1.f / (1.f + __expf(-g.x)); o.x = sg * xv.x + (1.f - sg) * fmaxf(nl.x, 0.f);
    sg = 1.f / (1.f + __expf(-g.y)); o.y = sg * xv.y + (1.f - sg) * fmaxf(nl.y, 0.f);
    sg = 1.f / (1.f + __expf(-g.z)); o.z = sg * xv.z + (1.f - sg) * fmaxf(nl.z, 0.f);
    sg = 1.f / (1.f + __expf(-g.w)); o.w = sg * xv.w + (1.f - sg) * fmaxf(nl.w, 0.f);
    if (outf)   *(float4*)(outf + (size_t)idx * 4) = o;
    if (out2)   store_split4(out2 + (size_t)r * RS + c4 * 4, o);
    if (oslice) *(float4*)(oslice + (size_t)r * (2 * HID) + c4 * 4) = o;
}

// ---------------------------------------------------------------------------
extern "C" void kernel_launch(void* const* d_in, const int* in_sizes, int n_in,
                              void* d_out, int out_size, void* d_ws, size_t ws_size,
                              hipStream_t stream)
{
    const float* inputs   = (const float*)d_in[0];
    const float* fw_lin_w = (const float*)d_in[2];
    const float* fw_lin_b = (const float*)d_in[3];
    const float* bw_lin_w = (const float*)d_in[4];
    const float* bw_lin_b = (const float*)d_in[5];
    const float* fw_hw_w  = (const float*)d_in[6];
    const float* fw_hw_b  = (const float*)d_in[7];
    const float* bw_hw_w  = (const float*)d_in[8];
    const float* bw_hw_b  = (const float*)d_in[9];
    const float* fw_pad   = (const float*)d_in[10];
    const float* bw_pad   = (const float*)d_in[11];
    const float* fw_rel   = (const float*)d_in[12];
    const float* bw_rel   = (const float*)d_in[13];
    float* out = (float*)d_out;
    float* ws  = (float*)d_ws;

    const size_t BSH  = (size_t)B * S * HID;      // 2,097,152 floats
    const size_t QKVF = (size_t)B * PAD * 1536;   // 6,488,064 floats per dir
    const int MP = B * PAD;                       // 4224
    const int MS = B * S;                         // 4096

    // grouped path needs 18,874,368 floats = 75,497,472 B
    const size_t GROUPED_BYTES = (size_t)18874368 * 4;
    const bool grouped = ws_size >= GROUPED_BYTES;
    const int G = grouped ? 2 : 1;

    float* f  = ws;
    float* bk = f + BSH;

    float* QKV[2]; float* ATT[2]; float* HWP[2];
    unsigned short* ACT2[2]; unsigned short* W2[2];
    if (grouped) {
        // qkv[z] overlays f/bk (dead between build_pad and the final gate)
        QKV[0] = ws;             QKV[1] = ws + QKVF;
        float* extra = ws + 2 * BSH;                       // 8,781,824 floats
        ATT[0] = extra;          ATT[1] = extra + (size_t)MP * HID;
        HWP[0] = extra;          HWP[1] = extra + (size_t)MS * 1024;
        unsigned short* a2 = (unsigned short*)(ws + 2 * QKVF);
        ACT2[0] = a2;            ACT2[1] = a2 + (size_t)MP * RS;
        unsigned short* w2 = a2 + 2 * (size_t)MP * RS;
        W2[0] = w2;              W2[1] = w2 + (size_t)1536 * RS;
    } else {
        float* qkvS = bk + BSH;                            // 25.9 MB
        QKV[0] = QKV[1] = qkvS;
        ATT[0] = ATT[1] = qkvS;                            // alias, qkv dead
        HWP[0] = HWP[1] = qkvS;                            // alias
        unsigned short* a2 = (unsigned short*)(qkvS + QKVF);
        ACT2[0] = ACT2[1] = a2;
        W2[0] = W2[1] = a2 + (size_t)MP * RS;
    }

    for (int l = 0; l < NLAYERS; ++l) {
        const float* LINW[2] = {fw_lin_w + (size_t)l * 4 * HID * HID,
                                bw_lin_w + (size_t)l * 4 * HID * HID};
        const float* LINB[2] = {fw_lin_b + (size_t)l * 4 * HID,
                                bw_lin_b + (size_t)l * 4 * HID};
        const float* HWW[2]  = {fw_hw_w + (size_t)l * NHW * 2 * HID * HID,
                                bw_hw_w + (size_t)l * NHW * 2 * HID * HID};
        const float* HWB[2]  = {fw_hw_b + (size_t)l * NHW * 2 * HID,
                                bw_hw_b + (size_t)l * NHW * 2 * HID};
        const float* RELW[2] = {fw_rel + (size_t)l * (WIDTH + 1),
                                bw_rel + (size_t)l * (WIDTH + 1)};
        const float* front = fw_pad + (size_t)l * WIDTH * HID;
        const float* back  = bw_pad + (size_t)l * WIDTH * HID;
        float* DST[2] = {f, bk};
        float* OSL[2] = {out + (size_t)l * B * S * 2 * HID,
                         out + (size_t)l * B * S * 2 * HID + HID};
        const float* SRC[2] = {(l == 0) ? inputs : f, (l == 0) ? inputs : bk};

        for (int d0 = 0; d0 < 2; d0 += G) {
            const int dB = (G == 2) ? 1 : d0;

            build_pad_split<<<dim3(MP * 128 / 256, 1, G), 256, 0, stream>>>(
                SRC[d0], SRC[dB], front, back, ACT2[0], ACT2[1]);

            conv_w<<<dim3(1536 * 128 / 256, 1, G), 256, 0, stream>>>(
                LINW[d0], LINW[dB], W2[0], W2[1]);
            gemm_split<<<dim3(1536 / 128, MP / 128, G), 256, 0, stream>>>(
                ACT2[0], W2[0], LINB[d0], QKV[0],
                ACT2[1], W2[1], LINB[dB], QKV[1], 1536);

            banded_attn<<<dim3(B * NHEADS * PAD / 4, 1, G), 256, 0, stream>>>(
                QKV[0], QKV[1], ACT2[0], ACT2[1], d0);

            conv_w<<<dim3(512 * 128 / 256, 1, G), 256, 0, stream>>>(
                LINW[d0] + 3 * (size_t)HID * HID, LINW[dB] + 3 * (size_t)HID * HID,
                W2[0], W2[1]);
            gemm_split<<<dim3(512 / 128, MP / 128, G), 256, 0, stream>>>(
                ACT2[0], W2[0], LINB[d0] + 3 * HID, ATT[0],
                ACT2[1], W2[1], LINB[dB] + 3 * HID, ATT[1], 512);

            rel_combine<<<dim3(MS * 128 / 256, 1, G), 256, 0, stream>>>(
                ATT[0], ATT[1], RELW[d0], RELW[dB], ACT2[0], ACT2[1],
                d0 * WIDTH, dB * WIDTH);

            for (int i = 0; i < NHW; ++i) {
                conv_w<<<dim3(1024 * 128 / 256, 1, G), 256, 0, stream>>>(
                    HWW[d0] + (size_t)i * 2 * HID * HID,
                    HWW[dB] + (size_t)i * 2 * HID * HID, W2[0], W2[1]);
                gemm_split<<<dim3(1024 / 128, MS / 128, G), 256, 0, stream>>>(
                    ACT2[0], W2[0], HWB[d0] + (size_t)i * 2 * HID, HWP[0],
                    ACT2[1], W2[1], HWB[dB] + (size_t)i * 2 * HID, HWP[1], 1024);
                const bool last = (i == NHW - 1);
                highway_gate<<<dim3(MS * 128 / 256, 1, G), 256, 0, stream>>>(
                    ACT2[0], ACT2[1], HWP[0], HWP[1],
                    last ? DST[d0] : (float*)nullptr,
                    last ? DST[dB] : (float*)nullptr,
                    last ? (unsigned short*)nullptr : ACT2[0],
                    last ? (unsigned short*)nullptr : ACT2[1],
                    last ? OSL[d0] : (float*)nullptr,
                    last ? OSL[dB] : (float*)nullptr);
            }
        }
    }
}